// Round 1
// baseline (5948.481 us; speedup 1.0000x reference)
//
#include <hip/hip_runtime.h>
#include <stdint.h>

#define VOCAB 32000
#define EMB   1024
#define HID   1024
#define BATCH 16
#define SEQ   256
#define MROWS (SEQ*BATCH)   // 4096

typedef unsigned short u16;
typedef __bf16 bf16x8 __attribute__((ext_vector_type(8)));
typedef float  f32x4  __attribute__((ext_vector_type(4)));

static __device__ __forceinline__ u16 f2bf(float f) {
  union { float f; uint32_t u; } v; v.f = f;
  return (u16)((v.u + 0x7FFFu + ((v.u >> 16) & 1u)) >> 16);  // RNE
}

static __device__ __forceinline__ f32x4 MFMA(bf16x8 a, bf16x8 b, f32x4 c) {
  return __builtin_amdgcn_mfma_f32_16x16x32_bf16(a, b, c, 0, 0, 0);
}

// ---------------- converts ----------------

// hidden (2,16,1024) f32 -> h0init/h1init bf16; also zero the barrier counter
__global__ void cvt_hidden(const float* __restrict__ hidden,
                           u16* __restrict__ h0i, u16* __restrict__ h1i,
                           unsigned* __restrict__ cnt) {
  int i = blockIdx.x * 256 + threadIdx.x;
  if (i == 0) *cnt = 0u;
  if (i < BATCH * HID)            h0i[i] = f2bf(hidden[i]);
  else if (i < 2 * BATCH * HID)   h1i[i - BATCH * HID] = f2bf(hidden[i]);
}

// (K=1024 x N=1024) f32 row-major  ->  (N,K) bf16
__global__ void transpose_cvt(const float* __restrict__ in, u16* __restrict__ out) {
  __shared__ float tile[32][33];
  int bx = blockIdx.x * 32;   // N
  int by = blockIdx.y * 32;   // K
  int tx = threadIdx.x, ty = threadIdx.y;   // (32,8)
  #pragma unroll
  for (int i = 0; i < 32; i += 8)
    tile[ty + i][tx] = in[(size_t)(by + ty + i) * HID + bx + tx];
  __syncthreads();
  #pragma unroll
  for (int i = 0; i < 32; i += 8)
    out[(size_t)(bx + ty + i) * HID + by + tx] = f2bf(tile[tx][ty + i]);
}

// plain f32 -> bf16 convert (emb_W, 32.77M elems)
__global__ void cvt_emb(const float4* __restrict__ in, ushort4* __restrict__ out, int n4) {
  int stride = gridDim.x * blockDim.x;
  for (int i = blockIdx.x * blockDim.x + threadIdx.x; i < n4; i += stride) {
    float4 v = in[i];
    ushort4 o; o.x = f2bf(v.x); o.y = f2bf(v.y); o.z = f2bf(v.z); o.w = f2bf(v.w);
    out[i] = o;
  }
}

// E[r = t*16+b] = bf16(emb_W[x[b][t]])
__global__ void gather_emb(const int* __restrict__ x, const float* __restrict__ embW,
                           u16* __restrict__ E) {
  int r = blockIdx.x;               // 0..4095
  int b = r & 15, t = r >> 4;
  int idx = x[b * SEQ + t];
  const float4* src = (const float4*)(embW + (size_t)idx * EMB);
  ushort4* dst = (ushort4*)(E + (size_t)r * EMB);
  float4 v = src[threadIdx.x];
  ushort4 o; o.x = f2bf(v.x); o.y = f2bf(v.y); o.z = f2bf(v.z); o.w = f2bf(v.w);
  dst[threadIdx.x] = o;
}

// ---------------- 128x128 MFMA GEMM, C = A(MxK) @ B(NxK)^T + bias ----------------
// OUTMODE 0: C[row*N+col] (fp32).  OUTMODE 1: logits remap row=t*16+b -> (b,t,col).
template <int OUTMODE>
__global__ __launch_bounds__(256) void gemm_bt(
    const u16* __restrict__ A, const u16* __restrict__ B,
    const float* __restrict__ bias, float* __restrict__ C,
    int M, int N, int K)
{
  __shared__ __align__(16) char lds[32768];
  char* As = lds;            // [128][64] bf16, chunk-XOR swizzled
  char* Bs = lds + 16384;
  const int tid  = threadIdx.x;
  const int lane = tid & 63;
  const int wave = tid >> 6;
  const int wr = wave >> 1, wc = wave & 1;     // 2x2 waves of 64x64
  const int bm = blockIdx.y * 128;
  const int bn = blockIdx.x * 128;
  const int srow = tid >> 3;                   // staging row 0..31
  const int swc  = (tid & 7) ^ (srow & 7);     // pre-swizzled source chunk (rule #21)

  f32x4 acc[4][4];
  #pragma unroll
  for (int i = 0; i < 4; ++i)
    #pragma unroll
    for (int j = 0; j < 4; ++j) acc[i][j] = (f32x4){0.f, 0.f, 0.f, 0.f};

  const u16* Ab = A + (size_t)(bm + srow) * K + swc * 8;
  const u16* Bb = B + (size_t)(bn + srow) * K + swc * 8;
  const size_t rstep = (size_t)32 * K;

  for (int k0 = 0; k0 < K; k0 += 64) {
    #pragma unroll
    for (int i = 0; i < 4; ++i) {
      __builtin_amdgcn_global_load_lds(
          (const __attribute__((address_space(1))) void*)(Ab + i * rstep + k0),
          (__attribute__((address_space(3))) void*)(As + i * 4096 + wave * 1024),
          16, 0, 0);
      __builtin_amdgcn_global_load_lds(
          (const __attribute__((address_space(1))) void*)(Bb + i * rstep + k0),
          (__attribute__((address_space(3))) void*)(Bs + i * 4096 + wave * 1024),
          16, 0, 0);
    }
    __syncthreads();   // drains vmcnt before use
    #pragma unroll
    for (int ks = 0; ks < 2; ++ks) {
      bf16x8 af[4], bq[4];
      #pragma unroll
      for (int mi = 0; mi < 4; ++mi) {
        int row = wr * 64 + mi * 16 + (lane & 15);
        int c = (ks * 4 + (lane >> 4)) ^ (row & 7);
        af[mi] = *(const bf16x8*)(As + row * 128 + c * 16);
      }
      #pragma unroll
      for (int ni = 0; ni < 4; ++ni) {
        int row = wc * 64 + ni * 16 + (lane & 15);
        int c = (ks * 4 + (lane >> 4)) ^ (row & 7);
        bq[ni] = *(const bf16x8*)(Bs + row * 128 + c * 16);
      }
      #pragma unroll
      for (int mi = 0; mi < 4; ++mi)
        #pragma unroll
        for (int ni = 0; ni < 4; ++ni)
          acc[mi][ni] = MFMA(af[mi], bq[ni], acc[mi][ni]);
    }
    __syncthreads();
  }

  #pragma unroll
  for (int mi = 0; mi < 4; ++mi) {
    #pragma unroll
    for (int ni = 0; ni < 4; ++ni) {
      const int col = bn + wc * 64 + ni * 16 + (lane & 15);
      const float bv = bias[col];
      #pragma unroll
      for (int j = 0; j < 4; ++j) {
        const int row = bm + wr * 64 + mi * 16 + ((lane >> 4) << 2) + j;
        const float v = acc[mi][ni][j] + bv;
        size_t off;
        if (OUTMODE == 0)
          off = (size_t)row * N + col;
        else
          off = (size_t)(row & 15) * ((size_t)SEQ * VOCAB) + (size_t)(row >> 4) * VOCAB + col;
        C[off] = v;
      }
    }
  }
}

// ---------------- fused 2-layer pipelined recurrence ----------------
// Phase s: layer-0 blocks (0..7, 128 cols each) compute h0(s);
//          layer-1 blocks (8..23, 64 cols each) compute h1(s-1) = tanh(h0(s-1)@Wx1 + h1(s-2)@Wh1 + b1).
// 257 phases, 1 grid barrier each (atomic counter + spin; 24 blocks always co-resident).
#define NB0 8
#define NB1 16
#define NBLK (NB0 + NB1)

static __device__ __forceinline__ void grid_barrier(unsigned* cnt, unsigned target) {
  __threadfence();            // release: stores visible device-wide
  __syncthreads();
  if (threadIdx.x == 0) {
    atomicAdd(cnt, 1u);
    while (__hip_atomic_load(cnt, __ATOMIC_RELAXED, __HIP_MEMORY_SCOPE_AGENT) < target)
      __builtin_amdgcn_s_sleep(2);
  }
  __syncthreads();
  __threadfence();            // acquire: invalidate stale caches
}

__global__ __launch_bounds__(256) void recurrence(
    const u16* __restrict__ Wh0T, const u16* __restrict__ Wx1T, const u16* __restrict__ Wh1T,
    const float* __restrict__ X0,       // 4096x1024 f32, already includes b0
    const float* __restrict__ b1,
    const u16* __restrict__ h0init, const u16* __restrict__ h1init,
    u16* __restrict__ H0, u16* __restrict__ H1,   // 4096x1024 bf16
    float* __restrict__ hidOut,                   // (2,16,1024) f32 at d_out tail
    unsigned* __restrict__ cnt)
{
  const int blk = blockIdx.x;
  const int lane = threadIdx.x & 63;
  const int wave = threadIdx.x >> 6;
  const int klane = (lane >> 4) * 8;    // k offset within MFMA frag
  const bool is0 = (blk < NB0);

  if (is0) {
    // layer 0: this wave owns 2 column tiles at c0, c0+16
    const int c0 = blk * 128 + wave * 32;
    const u16* W0 = Wh0T + (size_t)(c0 + (lane & 15)) * HID + klane;
    const u16* W1 = W0 + (size_t)16 * HID;
    for (int s = 0; s <= SEQ; ++s) {
      if (s < SEQ) {
        const u16* hsrc = (s == 0) ? h0init : (H0 + (size_t)(s - 1) * BATCH * HID);
        const u16* Ar = hsrc + (size_t)(lane & 15) * HID + klane;
        f32x4 a00 = {0,0,0,0}, a01 = {0,0,0,0}, a10 = {0,0,0,0}, a11 = {0,0,0,0};
        #pragma unroll 4
        for (int kk = 0; kk < 512; kk += 32) {
          bf16x8 alo = *(const bf16x8*)(Ar + kk);
          bf16x8 ahi = *(const bf16x8*)(Ar + 512 + kk);
          a00 = MFMA(alo, *(const bf16x8*)(W0 + kk),       a00);
          a01 = MFMA(ahi, *(const bf16x8*)(W0 + 512 + kk), a01);
          a10 = MFMA(alo, *(const bf16x8*)(W1 + kk),       a10);
          a11 = MFMA(ahi, *(const bf16x8*)(W1 + 512 + kk), a11);
        }
        f32x4 acc0 = a00 + a01, acc1 = a10 + a11;
        #pragma unroll
        for (int j = 0; j < 4; ++j) {
          const int b = ((lane >> 4) << 2) + j;
          const size_t ro = (size_t)(s * BATCH + b) * HID;
          const int col = c0 + (lane & 15);
          float v0 = tanhf(acc0[j] + X0[ro + col]);
          float v1 = tanhf(acc1[j] + X0[ro + col + 16]);
          H0[ro + col]      = f2bf(v0);
          H0[ro + col + 16] = f2bf(v1);
          if (s == SEQ - 1) {
            hidOut[(size_t)b * HID + col]      = v0;
            hidOut[(size_t)b * HID + col + 16] = v1;
          }
        }
      }
      if (s < SEQ) grid_barrier(cnt, (unsigned)(NBLK * (s + 1)));
    }
  } else {
    // layer 1: this wave owns 1 column tile at c1; K spans Wx1 (vs h0(t)) + Wh1 (vs h1(t-1))
    const int c1 = (blk - NB0) * 64 + wave * 16;
    const u16* Wx = Wx1T + (size_t)(c1 + (lane & 15)) * HID + klane;
    const u16* Wh = Wh1T + (size_t)(c1 + (lane & 15)) * HID + klane;
    const float bv = b1[c1 + (lane & 15)];
    for (int s = 0; s <= SEQ; ++s) {
      if (s >= 1) {
        const int t = s - 1;
        const u16* h0p = H0 + (size_t)t * BATCH * HID + (size_t)(lane & 15) * HID + klane;
        const u16* h1p = ((t == 0) ? h1init : (H1 + (size_t)(t - 1) * BATCH * HID))
                         + (size_t)(lane & 15) * HID + klane;
        f32x4 x0 = {0,0,0,0}, x1 = {0,0,0,0}, g0 = {0,0,0,0}, g1 = {0,0,0,0};
        #pragma unroll 4
        for (int kk = 0; kk < 512; kk += 32) {
          x0 = MFMA(*(const bf16x8*)(h0p + kk),       *(const bf16x8*)(Wx + kk),       x0);
          x1 = MFMA(*(const bf16x8*)(h0p + 512 + kk), *(const bf16x8*)(Wx + 512 + kk), x1);
          g0 = MFMA(*(const bf16x8*)(h1p + kk),       *(const bf16x8*)(Wh + kk),       g0);
          g1 = MFMA(*(const bf16x8*)(h1p + 512 + kk), *(const bf16x8*)(Wh + 512 + kk), g1);
        }
        f32x4 acc = (x0 + x1) + (g0 + g1);
        #pragma unroll
        for (int j = 0; j < 4; ++j) {
          const int b = ((lane >> 4) << 2) + j;
          const size_t ro = (size_t)(t * BATCH + b) * HID;
          const int col = c1 + (lane & 15);
          float v = tanhf(acc[j] + bv);
          H1[ro + col] = f2bf(v);
          if (t == SEQ - 1) hidOut[(size_t)BATCH * HID + (size_t)b * HID + col] = v;
        }
      }
      if (s < SEQ) grid_barrier(cnt, (unsigned)(NBLK * (s + 1)));
    }
  }
}

// ---------------- launch ----------------
extern "C" void kernel_launch(void* const* d_in, const int* in_sizes, int n_in,
                              void* d_out, int out_size, void* d_ws, size_t ws_size,
                              hipStream_t stream) {
  const int*   x      = (const int*)  d_in[0];
  const float* hidden = (const float*)d_in[1];
  const float* embW   = (const float*)d_in[2];
  const float* Wx0    = (const float*)d_in[3];
  const float* Wh0    = (const float*)d_in[4];
  const float* b0     = (const float*)d_in[5];
  const float* Wx1    = (const float*)d_in[6];
  const float* Wh1    = (const float*)d_in[7];
  const float* b1     = (const float*)d_in[8];
  const float* outb   = (const float*)d_in[9];
  float* out = (float*)d_out;

  char* ws = (char*)d_ws;
  size_t off = 0;
  auto alloc = [&](size_t bytes) {
    char* p = ws + off; off += (bytes + 255) & ~(size_t)255; return p;
  };
  u16*   embB = (u16*)  alloc((size_t)VOCAB * EMB * 2);
  u16*   Wx0T = (u16*)  alloc((size_t)EMB * HID * 2);
  u16*   Wh0T = (u16*)  alloc((size_t)HID * HID * 2);
  u16*   Wx1T = (u16*)  alloc((size_t)HID * HID * 2);
  u16*   Wh1T = (u16*)  alloc((size_t)HID * HID * 2);
  u16*   E    = (u16*)  alloc((size_t)MROWS * EMB * 2);
  float* X0f  = (float*)alloc((size_t)MROWS * HID * 4);
  u16*   H0   = (u16*)  alloc((size_t)MROWS * HID * 2);
  u16*   H1   = (u16*)  alloc((size_t)MROWS * HID * 2);
  u16*   h0i  = (u16*)  alloc((size_t)BATCH * HID * 2);
  u16*   h1i  = (u16*)  alloc((size_t)BATCH * HID * 2);
  unsigned* cnt = (unsigned*)alloc(256);
  if (off > ws_size) return;   // workspace too small -> loud failure

  cvt_hidden<<<dim3(128), dim3(256), 0, stream>>>(hidden, h0i, h1i, cnt);

  dim3 tb(32, 8), tg(32, 32);
  transpose_cvt<<<tg, tb, 0, stream>>>(Wx0, Wx0T);
  transpose_cvt<<<tg, tb, 0, stream>>>(Wh0, Wh0T);
  transpose_cvt<<<tg, tb, 0, stream>>>(Wx1, Wx1T);
  transpose_cvt<<<tg, tb, 0, stream>>>(Wh1, Wh1T);

  cvt_emb<<<dim3(2048), dim3(256), 0, stream>>>(
      (const float4*)embW, (ushort4*)embB, (int)((size_t)VOCAB * EMB / 4));
  gather_emb<<<dim3(MROWS), dim3(256), 0, stream>>>(x, embW, E);

  // X0 = E @ Wx0^T + b0   (4096x1024)
  gemm_bt<0><<<dim3(HID / 128, MROWS / 128), dim3(256), 0, stream>>>(
      E, Wx0T, b0, X0f, MROWS, HID, EMB);

  // fused recurrence: writes H0, H1 and final hidden into d_out tail
  recurrence<<<dim3(NBLK), dim3(256), 0, stream>>>(
      Wh0T, Wx1T, Wh1T, X0f, b1, h0i, h1i, H0, H1,
      out + (size_t)BATCH * SEQ * VOCAB, cnt);

  // logits = H1 @ emb^T + out_b   (4096x32000, remapped to (B,T,V))
  gemm_bt<1><<<dim3(VOCAB / 128, MROWS / 128), dim3(256), 0, stream>>>(
      H1, embB, outb, out, MROWS, VOCAB, EMB);
}

// Round 2
// 4028.233 us; speedup vs baseline: 1.4767x; 1.4767x over previous
//
#include <hip/hip_runtime.h>
#include <stdint.h>

#define VOCAB 32000
#define EMB   1024
#define HID   1024
#define BATCH 16
#define SEQ   256
#define MROWS (SEQ*BATCH)   // 4096

typedef unsigned short u16;
typedef __bf16 bf16x8 __attribute__((ext_vector_type(8)));
typedef float  f32x4  __attribute__((ext_vector_type(4)));

static __device__ __forceinline__ u16 f2bf(float f) {
  union { float f; uint32_t u; } v; v.f = f;
  return (u16)((v.u + 0x7FFFu + ((v.u >> 16) & 1u)) >> 16);  // RNE
}

static __device__ __forceinline__ f32x4 MFMA(bf16x8 a, bf16x8 b, f32x4 c) {
  return __builtin_amdgcn_mfma_f32_16x16x32_bf16(a, b, c, 0, 0, 0);
}

// ---------------- converts ----------------

__global__ void cvt_hidden(const float* __restrict__ hidden,
                           u16* __restrict__ h0i, u16* __restrict__ h1i,
                           unsigned* __restrict__ cnt) {
  int i = blockIdx.x * 256 + threadIdx.x;
  if (i == 0) *cnt = 0u;
  if (i < BATCH * HID)            h0i[i] = f2bf(hidden[i]);
  else if (i < 2 * BATCH * HID)   h1i[i - BATCH * HID] = f2bf(hidden[i]);
}

// (K=1024 x N=1024) f32 row-major  ->  (N,K) bf16
__global__ void transpose_cvt(const float* __restrict__ in, u16* __restrict__ out) {
  __shared__ float tile[32][33];
  int bx = blockIdx.x * 32;   // N
  int by = blockIdx.y * 32;   // K
  int tx = threadIdx.x, ty = threadIdx.y;   // (32,8)
  #pragma unroll
  for (int i = 0; i < 32; i += 8)
    tile[ty + i][tx] = in[(size_t)(by + ty + i) * HID + bx + tx];
  __syncthreads();
  #pragma unroll
  for (int i = 0; i < 32; i += 8)
    out[(size_t)(bx + ty + i) * HID + by + tx] = f2bf(tile[tx][ty + i]);
}

__global__ void cvt_emb(const float4* __restrict__ in, ushort4* __restrict__ out, int n4) {
  int stride = gridDim.x * blockDim.x;
  for (int i = blockIdx.x * blockDim.x + threadIdx.x; i < n4; i += stride) {
    float4 v = in[i];
    ushort4 o; o.x = f2bf(v.x); o.y = f2bf(v.y); o.z = f2bf(v.z); o.w = f2bf(v.w);
    out[i] = o;
  }
}

__global__ void gather_emb(const int* __restrict__ x, const float* __restrict__ embW,
                           u16* __restrict__ E) {
  int r = blockIdx.x;               // 0..4095
  int b = r & 15, t = r >> 4;
  int idx = x[b * SEQ + t];
  const float4* src = (const float4*)(embW + (size_t)idx * EMB);
  ushort4* dst = (ushort4*)(E + (size_t)r * EMB);
  float4 v = src[threadIdx.x];
  ushort4 o; o.x = f2bf(v.x); o.y = f2bf(v.y); o.z = f2bf(v.z); o.w = f2bf(v.w);
  dst[threadIdx.x] = o;
}

// ---------------- 128x128 MFMA GEMM, C = A(MxK) @ B(NxK)^T + bias ----------------
template <int OUTMODE>
__global__ __launch_bounds__(256) void gemm_bt(
    const u16* __restrict__ A, const u16* __restrict__ B,
    const float* __restrict__ bias, float* __restrict__ C,
    int M, int N, int K)
{
  __shared__ __align__(16) char lds[32768];
  char* As = lds;
  char* Bs = lds + 16384;
  const int tid  = threadIdx.x;
  const int lane = tid & 63;
  const int wave = tid >> 6;
  const int wr = wave >> 1, wc = wave & 1;
  const int bm = blockIdx.y * 128;
  const int bn = blockIdx.x * 128;
  const int srow = tid >> 3;
  const int swc  = (tid & 7) ^ (srow & 7);

  f32x4 acc[4][4];
  #pragma unroll
  for (int i = 0; i < 4; ++i)
    #pragma unroll
    for (int j = 0; j < 4; ++j) acc[i][j] = (f32x4){0.f, 0.f, 0.f, 0.f};

  const u16* Ab = A + (size_t)(bm + srow) * K + swc * 8;
  const u16* Bb = B + (size_t)(bn + srow) * K + swc * 8;
  const size_t rstep = (size_t)32 * K;

  for (int k0 = 0; k0 < K; k0 += 64) {
    #pragma unroll
    for (int i = 0; i < 4; ++i) {
      __builtin_amdgcn_global_load_lds(
          (const __attribute__((address_space(1))) void*)(Ab + i * rstep + k0),
          (__attribute__((address_space(3))) void*)(As + i * 4096 + wave * 1024),
          16, 0, 0);
      __builtin_amdgcn_global_load_lds(
          (const __attribute__((address_space(1))) void*)(Bb + i * rstep + k0),
          (__attribute__((address_space(3))) void*)(Bs + i * 4096 + wave * 1024),
          16, 0, 0);
    }
    __syncthreads();
    #pragma unroll
    for (int ks = 0; ks < 2; ++ks) {
      bf16x8 af[4], bq[4];
      #pragma unroll
      for (int mi = 0; mi < 4; ++mi) {
        int row = wr * 64 + mi * 16 + (lane & 15);
        int c = (ks * 4 + (lane >> 4)) ^ (row & 7);
        af[mi] = *(const bf16x8*)(As + row * 128 + c * 16);
      }
      #pragma unroll
      for (int ni = 0; ni < 4; ++ni) {
        int row = wc * 64 + ni * 16 + (lane & 15);
        int c = (ks * 4 + (lane >> 4)) ^ (row & 7);
        bq[ni] = *(const bf16x8*)(Bs + row * 128 + c * 16);
      }
      #pragma unroll
      for (int mi = 0; mi < 4; ++mi)
        #pragma unroll
        for (int ni = 0; ni < 4; ++ni)
          acc[mi][ni] = MFMA(af[mi], bq[ni], acc[mi][ni]);
    }
    __syncthreads();
  }

  #pragma unroll
  for (int mi = 0; mi < 4; ++mi) {
    #pragma unroll
    for (int ni = 0; ni < 4; ++ni) {
      const int col = bn + wc * 64 + ni * 16 + (lane & 15);
      const float bv = bias[col];
      #pragma unroll
      for (int j = 0; j < 4; ++j) {
        const int row = bm + wr * 64 + mi * 16 + ((lane >> 4) << 2) + j;
        const float v = acc[mi][ni][j] + bv;
        size_t off;
        if (OUTMODE == 0)
          off = (size_t)row * N + col;
        else
          off = (size_t)(row & 15) * ((size_t)SEQ * VOCAB) + (size_t)(row >> 4) * VOCAB + col;
        C[off] = v;
      }
    }
  }
}

// ---------------- fused 2-layer pipelined recurrence, weights in LDS ----------------
// 64 blocks: 0..31 layer0 (32 cols each, wave = colTile x K-half),
//            32..63 layer1 (32 cols each, wave = colTile x matrix{Wx1,Wh1}).
// Weights live in LDS (fence-immune); only h vectors cross the grid barrier.
#define NB0L 32
#define NB1L 32
#define NBLK (NB0L + NB1L)
#define COMB_OFF 131072

static __device__ __forceinline__ void grid_barrier(unsigned* cnt, unsigned target) {
  __threadfence();            // release: h stores visible device-wide
  __syncthreads();
  if (threadIdx.x == 0) {
    atomicAdd(cnt, 1u);
    while (__hip_atomic_load(cnt, __ATOMIC_RELAXED, __HIP_MEMORY_SCOPE_AGENT) < target)
      __builtin_amdgcn_s_sleep(2);
  }
  __syncthreads();
  __threadfence();            // acquire: invalidate stale caches
}

__global__ __launch_bounds__(256) void recurrence(
    const u16* __restrict__ Wh0T, const u16* __restrict__ Wx1T, const u16* __restrict__ Wh1T,
    const float* __restrict__ X0,       // 4096x1024 f32, includes b0
    const float* __restrict__ b1,
    const u16* __restrict__ h0init, const u16* __restrict__ h1init,
    u16* H0, u16* H1,                   // 4096x1024 bf16 (read+written across blocks)
    float* __restrict__ hidOut,         // (2,16,1024) f32 at d_out tail
    unsigned* cnt)
{
  __shared__ __align__(16) char lds[COMB_OFF + 2048];
  const int tid  = threadIdx.x;
  const int lane = tid & 63;
  const int wave = tid >> 6;
  const int l15  = lane & 15;
  const int lk   = lane >> 4;          // 0..3
  const int blk  = blockIdx.x;
  const bool is0 = (blk < NB0L);
  const int ct   = wave & 1;           // col-tile within block's 32 cols
  const int sel  = wave >> 1;          // layer0: K-half; layer1: matrix

  // ---- stage weight slice(s) into LDS, chunk-XOR swizzled ----
  if (is0) {
    const u16* src = Wh0T + (size_t)(blk * 32) * HID;
    for (int it = 0; it < 16; ++it) {
      int g = tid + it * 256;                     // 0..4095
      int row = g >> 7, ch = g & 127;
      bf16x8 v = *(const bf16x8*)(src + (size_t)row * HID + ch * 8);
      *(bf16x8*)(lds + row * 2048 + (((ch ^ (row & 7))) << 4)) = v;
    }
  } else {
    const int c1 = (blk - NB0L) * 32;
    const u16* s0 = Wx1T + (size_t)c1 * HID;
    const u16* s1 = Wh1T + (size_t)c1 * HID;
    for (int it = 0; it < 16; ++it) {
      int g = tid + it * 256;
      int row = g >> 7, ch = g & 127;
      int dsw = row * 2048 + (((ch ^ (row & 7))) << 4);
      bf16x8 v0 = *(const bf16x8*)(s0 + (size_t)row * HID + ch * 8);
      *(bf16x8*)(lds + dsw) = v0;
      bf16x8 v1 = *(const bf16x8*)(s1 + (size_t)row * HID + ch * 8);
      *(bf16x8*)(lds + 65536 + dsw) = v1;
    }
  }
  __syncthreads();

  const int brow  = ct * 16 + l15;     // W row (= output col) within the 32-row LDS tile
  const int rx    = brow & 7;
  const int rbase = brow * 2048;
  float* comb = (float*)(lds + COMB_OFF);

  if (is0) {
    const int col = blk * 32 + ct * 16 + l15;
    for (int s = 0; s <= SEQ; ++s) {
      if (s < SEQ) {
        const u16* hsrc = (s == 0) ? h0init : (H0 + (size_t)(s - 1) * BATCH * HID);
        const u16* Ap = hsrc + (size_t)l15 * HID + sel * 512 + lk * 8;
        f32x4 acc0 = {0,0,0,0}, acc1 = {0,0,0,0};
        #pragma unroll
        for (int m = 0; m < 8; ++m) {
          bf16x8 a = *(const bf16x8*)(Ap + m * 32);
          bf16x8 b = *(const bf16x8*)(lds + rbase + (((sel * 64 + m * 4 + lk) ^ rx) << 4));
          acc0 = MFMA(a, b, acc0);
        }
        #pragma unroll
        for (int m = 8; m < 16; ++m) {
          bf16x8 a = *(const bf16x8*)(Ap + m * 32);
          bf16x8 b = *(const bf16x8*)(lds + rbase + (((sel * 64 + m * 4 + lk) ^ rx) << 4));
          acc1 = MFMA(a, b, acc1);
        }
        f32x4 accv = acc0 + acc1;                 // this wave's K-half partial
        if (sel == 1) *(f32x4*)(comb + (ct * 64 + lane) * 4) = accv;
        __syncthreads();
        if (sel == 0) {
          f32x4 oth = *(const f32x4*)(comb + (ct * 64 + lane) * 4);
          #pragma unroll
          for (int j = 0; j < 4; ++j) {
            const int b = lk * 4 + j;
            const size_t ro = (size_t)(s * BATCH + b) * HID;
            float v = tanhf(accv[j] + oth[j] + X0[ro + col]);
            H0[ro + col] = f2bf(v);
            if (s == SEQ - 1) hidOut[(size_t)b * HID + col] = v;
          }
        }
      }
      if (s < SEQ) grid_barrier(cnt, (unsigned)(NBLK * (s + 1)));
    }
  } else {
    const int col = (blk - NB0L) * 32 + ct * 16 + l15;
    const float bv = b1[col];
    const char* wbase = lds + sel * 65536;
    for (int s = 0; s <= SEQ; ++s) {
      if (s >= 1) {
        const int t = s - 1;
        const u16* hsrc = sel ? ((t == 0) ? h1init : (H1 + (size_t)(t - 1) * BATCH * HID))
                              : (H0 + (size_t)t * BATCH * HID);
        const u16* Ap = hsrc + (size_t)l15 * HID + lk * 8;
        f32x4 acc0 = {0,0,0,0}, acc1 = {0,0,0,0};
        #pragma unroll
        for (int m = 0; m < 16; ++m) {
          bf16x8 a = *(const bf16x8*)(Ap + m * 32);
          bf16x8 b = *(const bf16x8*)(wbase + rbase + (((m * 4 + lk) ^ rx) << 4));
          acc0 = MFMA(a, b, acc0);
        }
        #pragma unroll
        for (int m = 16; m < 32; ++m) {
          bf16x8 a = *(const bf16x8*)(Ap + m * 32);
          bf16x8 b = *(const bf16x8*)(wbase + rbase + (((m * 4 + lk) ^ rx) << 4));
          acc1 = MFMA(a, b, acc1);
        }
        f32x4 accv = acc0 + acc1;                 // this wave's full-K, one matrix
        if (sel == 1) *(f32x4*)(comb + (ct * 64 + lane) * 4) = accv;
        __syncthreads();
        if (sel == 0) {
          f32x4 oth = *(const f32x4*)(comb + (ct * 64 + lane) * 4);
          #pragma unroll
          for (int j = 0; j < 4; ++j) {
            const int b = lk * 4 + j;
            const size_t ro = (size_t)(t * BATCH + b) * HID;
            float v = tanhf(accv[j] + oth[j] + bv);
            H1[ro + col] = f2bf(v);
            if (t == SEQ - 1) hidOut[(size_t)BATCH * HID + (size_t)b * HID + col] = v;
          }
        }
      }
      if (s < SEQ) grid_barrier(cnt, (unsigned)(NBLK * (s + 1)));
    }
  }
}

// ---------------- launch ----------------
extern "C" void kernel_launch(void* const* d_in, const int* in_sizes, int n_in,
                              void* d_out, int out_size, void* d_ws, size_t ws_size,
                              hipStream_t stream) {
  const int*   x      = (const int*)  d_in[0];
  const float* hidden = (const float*)d_in[1];
  const float* embW   = (const float*)d_in[2];
  const float* Wx0    = (const float*)d_in[3];
  const float* Wh0    = (const float*)d_in[4];
  const float* b0     = (const float*)d_in[5];
  const float* Wx1    = (const float*)d_in[6];
  const float* Wh1    = (const float*)d_in[7];
  const float* b1     = (const float*)d_in[8];
  const float* outb   = (const float*)d_in[9];
  float* out = (float*)d_out;

  char* ws = (char*)d_ws;
  size_t off = 0;
  auto alloc = [&](size_t bytes) {
    char* p = ws + off; off += (bytes + 255) & ~(size_t)255; return p;
  };
  u16*   embB = (u16*)  alloc((size_t)VOCAB * EMB * 2);
  u16*   Wx0T = (u16*)  alloc((size_t)EMB * HID * 2);
  u16*   Wh0T = (u16*)  alloc((size_t)HID * HID * 2);
  u16*   Wx1T = (u16*)  alloc((size_t)HID * HID * 2);
  u16*   Wh1T = (u16*)  alloc((size_t)HID * HID * 2);
  u16*   E    = (u16*)  alloc((size_t)MROWS * EMB * 2);
  float* X0f  = (float*)alloc((size_t)MROWS * HID * 4);
  u16*   H0   = (u16*)  alloc((size_t)MROWS * HID * 2);
  u16*   H1   = (u16*)  alloc((size_t)MROWS * HID * 2);
  u16*   h0i  = (u16*)  alloc((size_t)BATCH * HID * 2);
  u16*   h1i  = (u16*)  alloc((size_t)BATCH * HID * 2);
  unsigned* cnt = (unsigned*)alloc(256);
  if (off > ws_size) return;

  cvt_hidden<<<dim3(128), dim3(256), 0, stream>>>(hidden, h0i, h1i, cnt);

  dim3 tb(32, 8), tg(32, 32);
  transpose_cvt<<<tg, tb, 0, stream>>>(Wx0, Wx0T);
  transpose_cvt<<<tg, tb, 0, stream>>>(Wh0, Wh0T);
  transpose_cvt<<<tg, tb, 0, stream>>>(Wx1, Wx1T);
  transpose_cvt<<<tg, tb, 0, stream>>>(Wh1, Wh1T);

  cvt_emb<<<dim3(2048), dim3(256), 0, stream>>>(
      (const float4*)embW, (ushort4*)embB, (int)((size_t)VOCAB * EMB / 4));
  gather_emb<<<dim3(MROWS), dim3(256), 0, stream>>>(x, embW, E);

  // X0 = E @ Wx0^T + b0   (4096x1024)
  gemm_bt<0><<<dim3(HID / 128, MROWS / 128), dim3(256), 0, stream>>>(
      E, Wx0T, b0, X0f, MROWS, HID, EMB);

  // fused recurrence: writes H0, H1 and final hidden into d_out tail
  recurrence<<<dim3(NBLK), dim3(256), 0, stream>>>(
      Wh0T, Wx1T, Wh1T, X0f, b1, h0i, h1i, H0, H1,
      out + (size_t)BATCH * SEQ * VOCAB, cnt);

  // logits = H1 @ emb^T + out_b   (4096x32000, remapped to (B,T,V))
  gemm_bt<1><<<dim3(VOCAB / 128, MROWS / 128), dim3(256), 0, stream>>>(
      H1, embB, outb, out, MROWS, VOCAB, EMB);
}

// Round 3
// 2375.397 us; speedup vs baseline: 2.5042x; 1.6958x over previous
//
#include <hip/hip_runtime.h>
#include <stdint.h>

#define VOCAB 32000
#define EMB   1024
#define HID   1024
#define BATCH 16
#define SEQ   256
#define MROWS (SEQ*BATCH)   // 4096

typedef unsigned short u16;
typedef uint32_t u32;
typedef __bf16 bf16x8 __attribute__((ext_vector_type(8)));
typedef float  f32x4  __attribute__((ext_vector_type(4)));

static __device__ __forceinline__ u16 f2bf(float f) {
  union { float f; uint32_t u; } v; v.f = f;
  return (u16)((v.u + 0x7FFFu + ((v.u >> 16) & 1u)) >> 16);  // RNE
}

static __device__ __forceinline__ f32x4 MFMA(bf16x8 a, bf16x8 b, f32x4 c) {
  return __builtin_amdgcn_mfma_f32_16x16x32_bf16(a, b, c, 0, 0, 0);
}

// ---- coherent (XCD-bypass) memory helpers: batched loads, one wait ----
static __device__ __forceinline__ void load8_coh(const void* p, bf16x8* r) {
  asm volatile(
    "global_load_dwordx4 %0, %8, off sc0 sc1\n\t"
    "global_load_dwordx4 %1, %8, off offset:64 sc0 sc1\n\t"
    "global_load_dwordx4 %2, %8, off offset:128 sc0 sc1\n\t"
    "global_load_dwordx4 %3, %8, off offset:192 sc0 sc1\n\t"
    "global_load_dwordx4 %4, %8, off offset:256 sc0 sc1\n\t"
    "global_load_dwordx4 %5, %8, off offset:320 sc0 sc1\n\t"
    "global_load_dwordx4 %6, %8, off offset:384 sc0 sc1\n\t"
    "global_load_dwordx4 %7, %8, off offset:448 sc0 sc1\n\t"
    "s_waitcnt vmcnt(0)"
    : "=&v"(r[0]), "=&v"(r[1]), "=&v"(r[2]), "=&v"(r[3]),
      "=&v"(r[4]), "=&v"(r[5]), "=&v"(r[6]), "=&v"(r[7])
    : "v"(p) : "memory");
}

static __device__ __forceinline__ void load16_coh(const void* p, bf16x8* r) {
  asm volatile(
    "global_load_dwordx4 %0, %16, off sc0 sc1\n\t"
    "global_load_dwordx4 %1, %16, off offset:64 sc0 sc1\n\t"
    "global_load_dwordx4 %2, %16, off offset:128 sc0 sc1\n\t"
    "global_load_dwordx4 %3, %16, off offset:192 sc0 sc1\n\t"
    "global_load_dwordx4 %4, %16, off offset:256 sc0 sc1\n\t"
    "global_load_dwordx4 %5, %16, off offset:320 sc0 sc1\n\t"
    "global_load_dwordx4 %6, %16, off offset:384 sc0 sc1\n\t"
    "global_load_dwordx4 %7, %16, off offset:448 sc0 sc1\n\t"
    "global_load_dwordx4 %8, %16, off offset:512 sc0 sc1\n\t"
    "global_load_dwordx4 %9, %16, off offset:576 sc0 sc1\n\t"
    "global_load_dwordx4 %10, %16, off offset:640 sc0 sc1\n\t"
    "global_load_dwordx4 %11, %16, off offset:704 sc0 sc1\n\t"
    "global_load_dwordx4 %12, %16, off offset:768 sc0 sc1\n\t"
    "global_load_dwordx4 %13, %16, off offset:832 sc0 sc1\n\t"
    "global_load_dwordx4 %14, %16, off offset:896 sc0 sc1\n\t"
    "global_load_dwordx4 %15, %16, off offset:960 sc0 sc1\n\t"
    "s_waitcnt vmcnt(0)"
    : "=&v"(r[0]), "=&v"(r[1]), "=&v"(r[2]), "=&v"(r[3]),
      "=&v"(r[4]), "=&v"(r[5]), "=&v"(r[6]), "=&v"(r[7]),
      "=&v"(r[8]), "=&v"(r[9]), "=&v"(r[10]), "=&v"(r[11]),
      "=&v"(r[12]), "=&v"(r[13]), "=&v"(r[14]), "=&v"(r[15])
    : "v"(p) : "memory");
}

static __device__ __forceinline__ void store_u16_coh(u16* p, u16 v) {
  asm volatile("global_store_short %0, %1, off sc0 sc1"
               :: "v"(p), "v"((u32)v) : "memory");
}
static __device__ __forceinline__ void wait_vm0() {
  asm volatile("s_waitcnt vmcnt(0)" ::: "memory");
}

// ---------------- converts ----------------

__global__ void cvt_hidden(const float* __restrict__ hidden,
                           u16* __restrict__ h0i, u16* __restrict__ h1i,
                           unsigned* __restrict__ cnt) {
  int i = blockIdx.x * 256 + threadIdx.x;
  if (i == 0) *cnt = 0u;
  if (i < BATCH * HID)            h0i[i] = f2bf(hidden[i]);
  else if (i < 2 * BATCH * HID)   h1i[i - BATCH * HID] = f2bf(hidden[i]);
}

// (K=1024 x N=1024) f32 row-major  ->  (N,K) bf16
__global__ void transpose_cvt(const float* __restrict__ in, u16* __restrict__ out) {
  __shared__ float tile[32][33];
  int bx = blockIdx.x * 32;   // N
  int by = blockIdx.y * 32;   // K
  int tx = threadIdx.x, ty = threadIdx.y;   // (32,8)
  #pragma unroll
  for (int i = 0; i < 32; i += 8)
    tile[ty + i][tx] = in[(size_t)(by + ty + i) * HID + bx + tx];
  __syncthreads();
  #pragma unroll
  for (int i = 0; i < 32; i += 8)
    out[(size_t)(bx + ty + i) * HID + by + tx] = f2bf(tile[tx][ty + i]);
}

__global__ void cvt_emb(const float4* __restrict__ in, ushort4* __restrict__ out, int n4) {
  int stride = gridDim.x * blockDim.x;
  for (int i = blockIdx.x * blockDim.x + threadIdx.x; i < n4; i += stride) {
    float4 v = in[i];
    ushort4 o; o.x = f2bf(v.x); o.y = f2bf(v.y); o.z = f2bf(v.z); o.w = f2bf(v.w);
    out[i] = o;
  }
}

__global__ void gather_emb(const int* __restrict__ x, const float* __restrict__ embW,
                           u16* __restrict__ E) {
  int r = blockIdx.x;               // 0..4095
  int b = r & 15, t = r >> 4;
  int idx = x[b * SEQ + t];
  const float4* src = (const float4*)(embW + (size_t)idx * EMB);
  ushort4* dst = (ushort4*)(E + (size_t)r * EMB);
  float4 v = src[threadIdx.x];
  ushort4 o; o.x = f2bf(v.x); o.y = f2bf(v.y); o.z = f2bf(v.z); o.w = f2bf(v.w);
  dst[threadIdx.x] = o;
}

// ---------------- 128x128 MFMA GEMM, C = A(MxK) @ B(NxK)^T + bias ----------------
template <int OUTMODE>
__global__ __launch_bounds__(256) void gemm_bt(
    const u16* __restrict__ A, const u16* __restrict__ B,
    const float* __restrict__ bias, float* __restrict__ C,
    int M, int N, int K)
{
  __shared__ __align__(16) char lds[32768];
  char* As = lds;
  char* Bs = lds + 16384;
  const int tid  = threadIdx.x;
  const int lane = tid & 63;
  const int wave = tid >> 6;
  const int wr = wave >> 1, wc = wave & 1;
  const int bm = blockIdx.y * 128;
  const int bn = blockIdx.x * 128;
  const int srow = tid >> 3;
  const int swc  = (tid & 7) ^ (srow & 7);

  f32x4 acc[4][4];
  #pragma unroll
  for (int i = 0; i < 4; ++i)
    #pragma unroll
    for (int j = 0; j < 4; ++j) acc[i][j] = (f32x4){0.f, 0.f, 0.f, 0.f};

  const u16* Ab = A + (size_t)(bm + srow) * K + swc * 8;
  const u16* Bb = B + (size_t)(bn + srow) * K + swc * 8;
  const size_t rstep = (size_t)32 * K;

  for (int k0 = 0; k0 < K; k0 += 64) {
    #pragma unroll
    for (int i = 0; i < 4; ++i) {
      __builtin_amdgcn_global_load_lds(
          (const __attribute__((address_space(1))) void*)(Ab + i * rstep + k0),
          (__attribute__((address_space(3))) void*)(As + i * 4096 + wave * 1024),
          16, 0, 0);
      __builtin_amdgcn_global_load_lds(
          (const __attribute__((address_space(1))) void*)(Bb + i * rstep + k0),
          (__attribute__((address_space(3))) void*)(Bs + i * 4096 + wave * 1024),
          16, 0, 0);
    }
    __syncthreads();
    #pragma unroll
    for (int ks = 0; ks < 2; ++ks) {
      bf16x8 af[4], bq[4];
      #pragma unroll
      for (int mi = 0; mi < 4; ++mi) {
        int row = wr * 64 + mi * 16 + (lane & 15);
        int c = (ks * 4 + (lane >> 4)) ^ (row & 7);
        af[mi] = *(const bf16x8*)(As + row * 128 + c * 16);
      }
      #pragma unroll
      for (int ni = 0; ni < 4; ++ni) {
        int row = wc * 64 + ni * 16 + (lane & 15);
        int c = (ks * 4 + (lane >> 4)) ^ (row & 7);
        bq[ni] = *(const bf16x8*)(Bs + row * 128 + c * 16);
      }
      #pragma unroll
      for (int mi = 0; mi < 4; ++mi)
        #pragma unroll
        for (int ni = 0; ni < 4; ++ni)
          acc[mi][ni] = MFMA(af[mi], bq[ni], acc[mi][ni]);
    }
    __syncthreads();
  }

  #pragma unroll
  for (int mi = 0; mi < 4; ++mi) {
    #pragma unroll
    for (int ni = 0; ni < 4; ++ni) {
      const int col = bn + wc * 64 + ni * 16 + (lane & 15);
      const float bv = bias[col];
      #pragma unroll
      for (int j = 0; j < 4; ++j) {
        const int row = bm + wr * 64 + mi * 16 + ((lane >> 4) << 2) + j;
        const float v = acc[mi][ni][j] + bv;
        size_t off;
        if (OUTMODE == 0)
          off = (size_t)row * N + col;
        else
          off = (size_t)(row & 15) * ((size_t)SEQ * VOCAB) + (size_t)(row >> 4) * VOCAB + col;
        C[off] = v;
      }
    }
  }
}

// ---------------- fused 2-layer pipelined recurrence ----------------
// 64 blocks x 512 threads. Blocks 0..31: layer 0 (32 cols each; waves = K-quarter x col-tile).
// Blocks 32..63: layer 1 (32 cols each; waves = K-half x matrix x col-tile).
// Weights in LDS (layout [frag16B][brow] -> conflict-free reads). h exchanged via
// sc0sc1 coherent stores/loads; barrier = relaxed atomic counter, NO cache fences.
#define NB0L 32
#define NBLK 64
#define COMB_OFF 131072
#define LDS_TOTAL (COMB_OFF + 8192)

static __device__ __forceinline__ void gbar(unsigned* cnt, unsigned target) {
  __syncthreads();     // all waves have stored + drained vmcnt
  if (threadIdx.x == 0) {
    atomicAdd(cnt, 1u);
    while (__hip_atomic_load(cnt, __ATOMIC_RELAXED, __HIP_MEMORY_SCOPE_AGENT) < target)
      __builtin_amdgcn_s_sleep(2);
  }
  __syncthreads();
}

__global__ __launch_bounds__(512) void recurrence(
    const u16* __restrict__ Wh0T, const u16* __restrict__ Wx1T, const u16* __restrict__ Wh1T,
    const float* __restrict__ X0,       // 4096x1024 f32, includes b0
    const float* __restrict__ b1,
    const u16* __restrict__ h0init, const u16* __restrict__ h1init,
    u16* H0, u16* H1,                   // 4096x1024 bf16, coherent-exchanged
    float* __restrict__ hidOut,         // (2,16,1024) f32 at d_out tail
    unsigned* cnt)
{
  __shared__ __align__(16) char lds[LDS_TOTAL];
  const int tid  = threadIdx.x;
  const int lane = tid & 63;
  const int w    = tid >> 6;           // 0..7
  const int l15  = lane & 15;
  const int lk   = lane >> 4;          // 0..3
  const int blk  = blockIdx.x;
  const bool is0 = (blk < NB0L);
  float* comb = (float*)(lds + COMB_OFF);

  // ---- stage weight slice(s) into LDS: frag f = k/8 (16B), offset = f*512 + brow*16 ----
  if (is0) {
    const u16* src = Wh0T + (size_t)(blk * 32) * HID;
    for (int it = 0; it < 8; ++it) {
      int g = it * 512 + tid;                 // 0..4095
      int brow = g & 31, f = g >> 5;          // f 0..127
      *(bf16x8*)(lds + f * 512 + brow * 16) =
          *(const bf16x8*)(src + (size_t)brow * HID + f * 8);
    }
  } else {
    const u16* s0 = Wx1T + (size_t)((blk - NB0L) * 32) * HID;
    const u16* s1 = Wh1T + (size_t)((blk - NB0L) * 32) * HID;
    for (int it = 0; it < 8; ++it) {
      int g = it * 512 + tid;
      int brow = g & 31, f = g >> 5;
      int o = f * 512 + brow * 16;
      *(bf16x8*)(lds + o)         = *(const bf16x8*)(s0 + (size_t)brow * HID + f * 8);
      *(bf16x8*)(lds + 65536 + o) = *(const bf16x8*)(s1 + (size_t)brow * HID + f * 8);
    }
  }
  __syncthreads();

  if (is0) {
    const int q  = w >> 1;                    // K-quarter 0..3
    const int ct = w & 1;
    const int brow = ct * 16 + l15;
    const int col  = blk * 32 + brow;
    for (int s = 0; s <= SEQ; ++s) {
      if (s < SEQ) {
        const u16* hsrc = (s == 0) ? h0init : (H0 + (size_t)(s - 1) * BATCH * HID);
        const char* ap = (const char*)hsrc + l15 * 2048 + q * 512 + lk * 16;
        bf16x8 a[8];
        load8_coh(ap, a);
        float xv[4];
        if (w < 2) {
          #pragma unroll
          for (int j = 0; j < 4; ++j)
            xv[j] = X0[(size_t)(s * BATCH + lk * 4 + j) * HID + col];
        }
        f32x4 ae = {0,0,0,0}, ao = {0,0,0,0};
        #pragma unroll
        for (int m = 0; m < 8; m += 2) {
          ae = MFMA(a[m],     *(const bf16x8*)(lds + (q*32 + m*4 + lk)*512 + brow*16), ae);
          ao = MFMA(a[m + 1], *(const bf16x8*)(lds + (q*32 + (m+1)*4 + lk)*512 + brow*16), ao);
        }
        f32x4 acc = ae + ao;
        if (w >= 2) *(f32x4*)(comb + ((size_t)w * 64 + lane) * 4) = acc;
        __syncthreads();
        if (w < 2) {
          f32x4 p2 = *(const f32x4*)(comb + ((size_t)(w + 2) * 64 + lane) * 4);
          f32x4 p4 = *(const f32x4*)(comb + ((size_t)(w + 4) * 64 + lane) * 4);
          f32x4 p6 = *(const f32x4*)(comb + ((size_t)(w + 6) * 64 + lane) * 4);
          acc = (acc + p2) + (p4 + p6);
          #pragma unroll
          for (int j = 0; j < 4; ++j) {
            const int b = lk * 4 + j;
            float v = tanhf(acc[j] + xv[j]);
            store_u16_coh(H0 + (size_t)(s * BATCH + b) * HID + col, f2bf(v));
            if (s == SEQ - 1) hidOut[(size_t)b * HID + col] = v;
          }
          wait_vm0();
        }
      }
      if (s < SEQ) gbar(cnt, (unsigned)(NBLK * (s + 1)));
    }
  } else {
    const int kh  = w >> 2;                   // K-half
    const int mat = (w >> 1) & 1;             // 0: Wx1 (vs h0(t)), 1: Wh1 (vs h1(t-1))
    const int ct  = w & 1;
    const int brow = ct * 16 + l15;
    const int col  = (blk - NB0L) * 32 + brow;
    const float bv = b1[col];
    const char* wb = lds + mat * 65536;
    for (int s = 0; s <= SEQ; ++s) {
      if (s >= 1) {
        const int t = s - 1;
        const u16* hsrc = mat ? ((t == 0) ? h1init : (H1 + (size_t)(t - 1) * BATCH * HID))
                              : (H0 + (size_t)t * BATCH * HID);
        const char* ap = (const char*)hsrc + l15 * 2048 + kh * 1024 + lk * 16;
        bf16x8 a[16];
        load16_coh(ap, a);
        f32x4 ae = {0,0,0,0}, ao = {0,0,0,0};
        #pragma unroll
        for (int m = 0; m < 16; m += 2) {
          ae = MFMA(a[m],     *(const bf16x8*)(wb + (kh*64 + m*4 + lk)*512 + brow*16), ae);
          ao = MFMA(a[m + 1], *(const bf16x8*)(wb + (kh*64 + (m+1)*4 + lk)*512 + brow*16), ao);
        }
        f32x4 acc = ae + ao;
        if (w >= 2) *(f32x4*)(comb + ((size_t)w * 64 + lane) * 4) = acc;
        __syncthreads();
        if (w < 2) {
          f32x4 p2 = *(const f32x4*)(comb + ((size_t)(w + 2) * 64 + lane) * 4);
          f32x4 p4 = *(const f32x4*)(comb + ((size_t)(w + 4) * 64 + lane) * 4);
          f32x4 p6 = *(const f32x4*)(comb + ((size_t)(w + 6) * 64 + lane) * 4);
          acc = (acc + p2) + (p4 + p6);
          #pragma unroll
          for (int j = 0; j < 4; ++j) {
            const int b = lk * 4 + j;
            float v = tanhf(acc[j] + bv);
            store_u16_coh(H1 + (size_t)(t * BATCH + b) * HID + col, f2bf(v));
            if (t == SEQ - 1) hidOut[(size_t)(BATCH * HID) + (size_t)b * HID + col] = v;
          }
          wait_vm0();
        }
      }
      if (s < SEQ) gbar(cnt, (unsigned)(NBLK * (s + 1)));
    }
  }
}

// ---------------- launch ----------------
extern "C" void kernel_launch(void* const* d_in, const int* in_sizes, int n_in,
                              void* d_out, int out_size, void* d_ws, size_t ws_size,
                              hipStream_t stream) {
  const int*   x      = (const int*)  d_in[0];
  const float* hidden = (const float*)d_in[1];
  const float* embW   = (const float*)d_in[2];
  const float* Wx0    = (const float*)d_in[3];
  const float* Wh0    = (const float*)d_in[4];
  const float* b0     = (const float*)d_in[5];
  const float* Wx1    = (const float*)d_in[6];
  const float* Wh1    = (const float*)d_in[7];
  const float* b1     = (const float*)d_in[8];
  const float* outb   = (const float*)d_in[9];
  float* out = (float*)d_out;

  char* ws = (char*)d_ws;
  size_t off = 0;
  auto alloc = [&](size_t bytes) {
    char* p = ws + off; off += (bytes + 255) & ~(size_t)255; return p;
  };
  u16*   embB = (u16*)  alloc((size_t)VOCAB * EMB * 2);
  u16*   Wx0T = (u16*)  alloc((size_t)EMB * HID * 2);
  u16*   Wh0T = (u16*)  alloc((size_t)HID * HID * 2);
  u16*   Wx1T = (u16*)  alloc((size_t)HID * HID * 2);
  u16*   Wh1T = (u16*)  alloc((size_t)HID * HID * 2);
  u16*   E    = (u16*)  alloc((size_t)MROWS * EMB * 2);
  float* X0f  = (float*)alloc((size_t)MROWS * HID * 4);
  u16*   H0   = (u16*)  alloc((size_t)MROWS * HID * 2);
  u16*   H1   = (u16*)  alloc((size_t)MROWS * HID * 2);
  u16*   h0i  = (u16*)  alloc((size_t)BATCH * HID * 2);
  u16*   h1i  = (u16*)  alloc((size_t)BATCH * HID * 2);
  unsigned* cnt = (unsigned*)alloc(256);
  if (off > ws_size) return;

  cvt_hidden<<<dim3(128), dim3(256), 0, stream>>>(hidden, h0i, h1i, cnt);

  dim3 tb(32, 8), tg(32, 32);
  transpose_cvt<<<tg, tb, 0, stream>>>(Wx0, Wx0T);
  transpose_cvt<<<tg, tb, 0, stream>>>(Wh0, Wh0T);
  transpose_cvt<<<tg, tb, 0, stream>>>(Wx1, Wx1T);
  transpose_cvt<<<tg, tb, 0, stream>>>(Wh1, Wh1T);

  cvt_emb<<<dim3(2048), dim3(256), 0, stream>>>(
      (const float4*)embW, (ushort4*)embB, (int)((size_t)VOCAB * EMB / 4));
  gather_emb<<<dim3(MROWS), dim3(256), 0, stream>>>(x, embW, E);

  // X0 = E @ Wx0^T + b0   (4096x1024)
  gemm_bt<0><<<dim3(HID / 128, MROWS / 128), dim3(256), 0, stream>>>(
      E, Wx0T, b0, X0f, MROWS, HID, EMB);

  // fused recurrence: writes H0, H1 and final hidden into d_out tail
  recurrence<<<dim3(NBLK), dim3(512), 0, stream>>>(
      Wh0T, Wx1T, Wh1T, X0f, b1, h0i, h1i, H0, H1,
      out + (size_t)BATCH * SEQ * VOCAB, cnt);

  // logits = H1 @ emb^T + out_b   (4096x32000, remapped to (B,T,V))
  gemm_bt<1><<<dim3(VOCAB / 128, MROWS / 128), dim3(256), 0, stream>>>(
      H1, embB, outb, out, MROWS, VOCAB, EMB);
}

// Round 4
// 2294.973 us; speedup vs baseline: 2.5920x; 1.0350x over previous
//
#include <hip/hip_runtime.h>
#include <stdint.h>

#define VOCAB 32000
#define EMB   1024
#define HID   1024
#define BATCH 16
#define SEQ   256
#define MROWS (SEQ*BATCH)   // 4096

typedef unsigned short u16;
typedef uint32_t u32;
typedef __bf16 bf16x8 __attribute__((ext_vector_type(8)));
typedef float  f32x4  __attribute__((ext_vector_type(4)));

static __device__ __forceinline__ u16 f2bf(float f) {
  union { float f; uint32_t u; } v; v.f = f;
  return (u16)((v.u + 0x7FFFu + ((v.u >> 16) & 1u)) >> 16);  // RNE
}

static __device__ __forceinline__ f32x4 MFMA(bf16x8 a, bf16x8 b, f32x4 c) {
  return __builtin_amdgcn_mfma_f32_16x16x32_bf16(a, b, c, 0, 0, 0);
}

// ---- coherent (XCD-bypass) memory helpers: batched loads, one wait ----
static __device__ __forceinline__ void load8_coh(const void* p, bf16x8* r) {
  asm volatile(
    "global_load_dwordx4 %0, %8, off sc0 sc1\n\t"
    "global_load_dwordx4 %1, %8, off offset:64 sc0 sc1\n\t"
    "global_load_dwordx4 %2, %8, off offset:128 sc0 sc1\n\t"
    "global_load_dwordx4 %3, %8, off offset:192 sc0 sc1\n\t"
    "global_load_dwordx4 %4, %8, off offset:256 sc0 sc1\n\t"
    "global_load_dwordx4 %5, %8, off offset:320 sc0 sc1\n\t"
    "global_load_dwordx4 %6, %8, off offset:384 sc0 sc1\n\t"
    "global_load_dwordx4 %7, %8, off offset:448 sc0 sc1\n\t"
    "s_waitcnt vmcnt(0)"
    : "=&v"(r[0]), "=&v"(r[1]), "=&v"(r[2]), "=&v"(r[3]),
      "=&v"(r[4]), "=&v"(r[5]), "=&v"(r[6]), "=&v"(r[7])
    : "v"(p) : "memory");
}

static __device__ __forceinline__ void load16_coh(const void* p, bf16x8* r) {
  asm volatile(
    "global_load_dwordx4 %0, %16, off sc0 sc1\n\t"
    "global_load_dwordx4 %1, %16, off offset:64 sc0 sc1\n\t"
    "global_load_dwordx4 %2, %16, off offset:128 sc0 sc1\n\t"
    "global_load_dwordx4 %3, %16, off offset:192 sc0 sc1\n\t"
    "global_load_dwordx4 %4, %16, off offset:256 sc0 sc1\n\t"
    "global_load_dwordx4 %5, %16, off offset:320 sc0 sc1\n\t"
    "global_load_dwordx4 %6, %16, off offset:384 sc0 sc1\n\t"
    "global_load_dwordx4 %7, %16, off offset:448 sc0 sc1\n\t"
    "global_load_dwordx4 %8, %16, off offset:512 sc0 sc1\n\t"
    "global_load_dwordx4 %9, %16, off offset:576 sc0 sc1\n\t"
    "global_load_dwordx4 %10, %16, off offset:640 sc0 sc1\n\t"
    "global_load_dwordx4 %11, %16, off offset:704 sc0 sc1\n\t"
    "global_load_dwordx4 %12, %16, off offset:768 sc0 sc1\n\t"
    "global_load_dwordx4 %13, %16, off offset:832 sc0 sc1\n\t"
    "global_load_dwordx4 %14, %16, off offset:896 sc0 sc1\n\t"
    "global_load_dwordx4 %15, %16, off offset:960 sc0 sc1\n\t"
    "s_waitcnt vmcnt(0)"
    : "=&v"(r[0]), "=&v"(r[1]), "=&v"(r[2]), "=&v"(r[3]),
      "=&v"(r[4]), "=&v"(r[5]), "=&v"(r[6]), "=&v"(r[7]),
      "=&v"(r[8]), "=&v"(r[9]), "=&v"(r[10]), "=&v"(r[11]),
      "=&v"(r[12]), "=&v"(r[13]), "=&v"(r[14]), "=&v"(r[15])
    : "v"(p) : "memory");
}

static __device__ __forceinline__ void store_u16_coh(u16* p, u16 v) {
  asm volatile("global_store_short %0, %1, off sc0 sc1"
               :: "v"(p), "v"((u32)v) : "memory");
}
static __device__ __forceinline__ void wait_vm0() {
  asm volatile("s_waitcnt vmcnt(0)" ::: "memory");
}

// relaxed agent-scope spin until *p >= tgt (no cache fences, no sleep)
static __device__ __forceinline__ void spin_ge(const unsigned* p, unsigned tgt) {
  while (__hip_atomic_load(p, __ATOMIC_RELAXED, __HIP_MEMORY_SCOPE_AGENT) < tgt) {}
}

// ---------------- converts ----------------

// hidden -> bf16 init vectors; also zero the per-step flag arrays (16384 u32)
__global__ void cvt_hidden(const float* __restrict__ hidden,
                           u16* __restrict__ h0i, u16* __restrict__ h1i,
                           unsigned* __restrict__ flags) {
  int i = blockIdx.x * 256 + threadIdx.x;
  if (i < 16384) flags[i] = 0u;
  if (i < BATCH * HID)            h0i[i] = f2bf(hidden[i]);
  else if (i < 2 * BATCH * HID)   h1i[i - BATCH * HID] = f2bf(hidden[i]);
}

// (K=1024 x N=1024) f32 row-major  ->  (N,K) bf16
__global__ void transpose_cvt(const float* __restrict__ in, u16* __restrict__ out) {
  __shared__ float tile[32][33];
  int bx = blockIdx.x * 32;   // N
  int by = blockIdx.y * 32;   // K
  int tx = threadIdx.x, ty = threadIdx.y;   // (32,8)
  #pragma unroll
  for (int i = 0; i < 32; i += 8)
    tile[ty + i][tx] = in[(size_t)(by + ty + i) * HID + bx + tx];
  __syncthreads();
  #pragma unroll
  for (int i = 0; i < 32; i += 8)
    out[(size_t)(bx + ty + i) * HID + by + tx] = f2bf(tile[tx][ty + i]);
}

__global__ void cvt_emb(const float4* __restrict__ in, ushort4* __restrict__ out, int n4) {
  int stride = gridDim.x * blockDim.x;
  for (int i = blockIdx.x * blockDim.x + threadIdx.x; i < n4; i += stride) {
    float4 v = in[i];
    ushort4 o; o.x = f2bf(v.x); o.y = f2bf(v.y); o.z = f2bf(v.z); o.w = f2bf(v.w);
    out[i] = o;
  }
}

__global__ void gather_emb(const int* __restrict__ x, const float* __restrict__ embW,
                           u16* __restrict__ E) {
  int r = blockIdx.x;               // 0..4095
  int b = r & 15, t = r >> 4;
  int idx = x[b * SEQ + t];
  const float4* src = (const float4*)(embW + (size_t)idx * EMB);
  ushort4* dst = (ushort4*)(E + (size_t)r * EMB);
  float4 v = src[threadIdx.x];
  ushort4 o; o.x = f2bf(v.x); o.y = f2bf(v.y); o.z = f2bf(v.z); o.w = f2bf(v.w);
  dst[threadIdx.x] = o;
}

// ---------------- 128x128 MFMA GEMM, C = A(MxK) @ B(NxK)^T + bias ----------------
template <int OUTMODE>
__global__ __launch_bounds__(256) void gemm_bt(
    const u16* __restrict__ A, const u16* __restrict__ B,
    const float* __restrict__ bias, float* __restrict__ C,
    int M, int N, int K)
{
  __shared__ __align__(16) char lds[32768];
  char* As = lds;
  char* Bs = lds + 16384;
  const int tid  = threadIdx.x;
  const int lane = tid & 63;
  const int wave = tid >> 6;
  const int wr = wave >> 1, wc = wave & 1;
  const int bm = blockIdx.y * 128;
  const int bn = blockIdx.x * 128;
  const int srow = tid >> 3;
  const int swc  = (tid & 7) ^ (srow & 7);

  f32x4 acc[4][4];
  #pragma unroll
  for (int i = 0; i < 4; ++i)
    #pragma unroll
    for (int j = 0; j < 4; ++j) acc[i][j] = (f32x4){0.f, 0.f, 0.f, 0.f};

  const u16* Ab = A + (size_t)(bm + srow) * K + swc * 8;
  const u16* Bb = B + (size_t)(bn + srow) * K + swc * 8;
  const size_t rstep = (size_t)32 * K;

  for (int k0 = 0; k0 < K; k0 += 64) {
    #pragma unroll
    for (int i = 0; i < 4; ++i) {
      __builtin_amdgcn_global_load_lds(
          (const __attribute__((address_space(1))) void*)(Ab + i * rstep + k0),
          (__attribute__((address_space(3))) void*)(As + i * 4096 + wave * 1024),
          16, 0, 0);
      __builtin_amdgcn_global_load_lds(
          (const __attribute__((address_space(1))) void*)(Bb + i * rstep + k0),
          (__attribute__((address_space(3))) void*)(Bs + i * 4096 + wave * 1024),
          16, 0, 0);
    }
    __syncthreads();
    #pragma unroll
    for (int ks = 0; ks < 2; ++ks) {
      bf16x8 af[4], bq[4];
      #pragma unroll
      for (int mi = 0; mi < 4; ++mi) {
        int row = wr * 64 + mi * 16 + (lane & 15);
        int c = (ks * 4 + (lane >> 4)) ^ (row & 7);
        af[mi] = *(const bf16x8*)(As + row * 128 + c * 16);
      }
      #pragma unroll
      for (int ni = 0; ni < 4; ++ni) {
        int row = wc * 64 + ni * 16 + (lane & 15);
        int c = (ks * 4 + (lane >> 4)) ^ (row & 7);
        bq[ni] = *(const bf16x8*)(Bs + row * 128 + c * 16);
      }
      #pragma unroll
      for (int mi = 0; mi < 4; ++mi)
        #pragma unroll
        for (int ni = 0; ni < 4; ++ni)
          acc[mi][ni] = MFMA(af[mi], bq[ni], acc[mi][ni]);
    }
    __syncthreads();
  }

  #pragma unroll
  for (int mi = 0; mi < 4; ++mi) {
    #pragma unroll
    for (int ni = 0; ni < 4; ++ni) {
      const int col = bn + wc * 64 + ni * 16 + (lane & 15);
      const float bv = bias[col];
      #pragma unroll
      for (int j = 0; j < 4; ++j) {
        const int row = bm + wr * 64 + mi * 16 + ((lane >> 4) << 2) + j;
        const float v = acc[mi][ni][j] + bv;
        size_t off;
        if (OUTMODE == 0)
          off = (size_t)row * N + col;
        else
          off = (size_t)(row & 15) * ((size_t)SEQ * VOCAB) + (size_t)(row >> 4) * VOCAB + col;
        C[off] = v;
      }
    }
  }
}

// ---------------- fused 2-layer recurrence, split dataflow flags ----------------
// 64 blocks x 512 threads. Blocks 0..31: layer 0; blocks 32..63: layer 1.
// flags[s*32]         = cnt0[s]  (# layer-0 blocks that published h0(s))
// flags[8192 + t*32]  = cnt1[t]  (# layer-1 blocks that published h1(t))
// layer-0(s) waits cnt0[s-1]==32; layer-1(t) waits cnt0[t]==32 && cnt1[t-1]==32.
// No global barrier, no cache fences; h via sc0sc1 write-through/coherent loads.
#define NB0L 32
#define NBLK 64
#define COMB_OFF 131072
#define LDS_TOTAL (COMB_OFF + 8192)

__global__ __launch_bounds__(512) void recurrence(
    const u16* __restrict__ Wh0T, const u16* __restrict__ Wx1T, const u16* __restrict__ Wh1T,
    const float* __restrict__ X0,       // 4096x1024 f32, includes b0
    const float* __restrict__ b1,
    const u16* __restrict__ h0init, const u16* __restrict__ h1init,
    u16* H0, u16* H1,                   // 4096x1024 bf16, coherent-exchanged
    float* __restrict__ hidOut,         // (2,16,1024) f32 at d_out tail
    unsigned* flags)
{
  __shared__ __align__(16) char lds[LDS_TOTAL];
  const int tid  = threadIdx.x;
  const int lane = tid & 63;
  const int w    = tid >> 6;           // 0..7
  const int l15  = lane & 15;
  const int lk   = lane >> 4;          // 0..3
  const int blk  = blockIdx.x;
  const bool is0 = (blk < NB0L);
  float* comb = (float*)(lds + COMB_OFF);
  unsigned* c0 = flags;
  unsigned* c1 = flags + 8192;

  // ---- stage weight slice(s) into LDS: frag f = k/8 (16B), offset = f*512 + brow*16 ----
  if (is0) {
    const u16* src = Wh0T + (size_t)(blk * 32) * HID;
    for (int it = 0; it < 8; ++it) {
      int g = it * 512 + tid;                 // 0..4095
      int brow = g & 31, f = g >> 5;          // f 0..127
      *(bf16x8*)(lds + f * 512 + brow * 16) =
          *(const bf16x8*)(src + (size_t)brow * HID + f * 8);
    }
  } else {
    const u16* s0 = Wx1T + (size_t)((blk - NB0L) * 32) * HID;
    const u16* s1 = Wh1T + (size_t)((blk - NB0L) * 32) * HID;
    for (int it = 0; it < 8; ++it) {
      int g = it * 512 + tid;
      int brow = g & 31, f = g >> 5;
      int o = f * 512 + brow * 16;
      *(bf16x8*)(lds + o)         = *(const bf16x8*)(s0 + (size_t)brow * HID + f * 8);
      *(bf16x8*)(lds + 65536 + o) = *(const bf16x8*)(s1 + (size_t)brow * HID + f * 8);
    }
  }
  __syncthreads();

  if (is0) {
    const int q  = w >> 1;                    // K-quarter 0..3
    const int ct = w & 1;
    const int brow = ct * 16 + l15;
    const int col  = blk * 32 + brow;
    float xv[4];
    if (w < 2) {
      #pragma unroll
      for (int j = 0; j < 4; ++j)
        xv[j] = X0[(size_t)(lk * 4 + j) * HID + col];     // s = 0
    }
    for (int s = 0; s < SEQ; ++s) {
      // entry invariant: cnt0[s-1]==32 (enforced by end-of-prev-iter spin)
      const u16* hsrc = (s == 0) ? h0init : (H0 + (size_t)(s - 1) * BATCH * HID);
      const char* ap = (const char*)hsrc + l15 * 2048 + q * 512 + lk * 16;
      bf16x8 a[8];
      load8_coh(ap, a);
      f32x4 ae = {0,0,0,0}, ao = {0,0,0,0};
      #pragma unroll
      for (int m = 0; m < 8; m += 2) {
        ae = MFMA(a[m],     *(const bf16x8*)(lds + (q*32 + m*4 + lk)*512 + brow*16), ae);
        ao = MFMA(a[m + 1], *(const bf16x8*)(lds + (q*32 + (m+1)*4 + lk)*512 + brow*16), ao);
      }
      f32x4 acc = ae + ao;
      if (w >= 2) *(f32x4*)(comb + ((size_t)w * 64 + lane) * 4) = acc;
      __syncthreads();
      if (w < 2) {
        f32x4 p2 = *(const f32x4*)(comb + ((size_t)(w + 2) * 64 + lane) * 4);
        f32x4 p4 = *(const f32x4*)(comb + ((size_t)(w + 4) * 64 + lane) * 4);
        f32x4 p6 = *(const f32x4*)(comb + ((size_t)(w + 6) * 64 + lane) * 4);
        acc = (acc + p2) + (p4 + p6);
        #pragma unroll
        for (int j = 0; j < 4; ++j) {
          const int b = lk * 4 + j;
          float v = tanhf(acc[j] + xv[j]);
          store_u16_coh(H0 + (size_t)(s * BATCH + b) * HID + col, f2bf(v));
          if (s == SEQ - 1) hidOut[(size_t)b * HID + col] = v;
        }
        wait_vm0();
        if (s + 1 < SEQ) {                    // prefetch X0 for next step
          #pragma unroll
          for (int j = 0; j < 4; ++j)
            xv[j] = X0[(size_t)((s + 1) * BATCH + lk * 4 + j) * HID + col];
        }
      }
      __syncthreads();
      if (tid == 0) {
        atomicAdd(c0 + (size_t)s * 32, 1u);   // publish h0(s)
        if (s + 1 < SEQ) spin_ge(c0 + (size_t)s * 32, NB0L);  // dep for step s+1
      }
      __syncthreads();
    }
  } else {
    const int kh  = w >> 2;                   // K-half
    const int mat = (w >> 1) & 1;             // 0: Wx1 (vs h0(t)), 1: Wh1 (vs h1(t-1))
    const int ct  = w & 1;
    const int brow = ct * 16 + l15;
    const int col  = (blk - NB0L) * 32 + brow;
    const float bv = b1[col];
    const char* wb = lds + mat * 65536;
    if (tid == 0) spin_ge(c0, NB0L);          // wait for h0(0)
    __syncthreads();
    for (int t = 0; t < SEQ; ++t) {
      // entry invariant: cnt0[t]==32 and (t==0 || cnt1[t-1]==32)
      const u16* hsrc = mat ? ((t == 0) ? h1init : (H1 + (size_t)(t - 1) * BATCH * HID))
                            : (H0 + (size_t)t * BATCH * HID);
      const char* ap = (const char*)hsrc + l15 * 2048 + kh * 1024 + lk * 16;
      bf16x8 a[16];
      load16_coh(ap, a);
      f32x4 ae = {0,0,0,0}, ao = {0,0,0,0};
      #pragma unroll
      for (int m = 0; m < 16; m += 2) {
        ae = MFMA(a[m],     *(const bf16x8*)(wb + (kh*64 + m*4 + lk)*512 + brow*16), ae);
        ao = MFMA(a[m + 1], *(const bf16x8*)(wb + (kh*64 + (m+1)*4 + lk)*512 + brow*16), ao);
      }
      f32x4 acc = ae + ao;
      if (w >= 2) *(f32x4*)(comb + ((size_t)w * 64 + lane) * 4) = acc;
      __syncthreads();
      if (w < 2) {
        f32x4 p2 = *(const f32x4*)(comb + ((size_t)(w + 2) * 64 + lane) * 4);
        f32x4 p4 = *(const f32x4*)(comb + ((size_t)(w + 4) * 64 + lane) * 4);
        f32x4 p6 = *(const f32x4*)(comb + ((size_t)(w + 6) * 64 + lane) * 4);
        acc = (acc + p2) + (p4 + p6);
        #pragma unroll
        for (int j = 0; j < 4; ++j) {
          const int b = lk * 4 + j;
          float v = tanhf(acc[j] + bv);
          store_u16_coh(H1 + (size_t)(t * BATCH + b) * HID + col, f2bf(v));
          if (t == SEQ - 1) hidOut[(size_t)(BATCH * HID) + (size_t)b * HID + col] = v;
        }
        wait_vm0();
      }
      __syncthreads();
      if (t + 1 < SEQ) {
        if (tid == 0) {
          atomicAdd(c1 + (size_t)t * 32, 1u);                 // publish h1(t)
          spin_ge(c0 + (size_t)(t + 1) * 32, NB0L);           // h0(t+1) ready?
        }
        if (tid == 64) spin_ge(c1 + (size_t)t * 32, NBLK - NB0L);  // h1(t) ready?
      }
      __syncthreads();
    }
  }
}

// ---------------- launch ----------------
extern "C" void kernel_launch(void* const* d_in, const int* in_sizes, int n_in,
                              void* d_out, int out_size, void* d_ws, size_t ws_size,
                              hipStream_t stream) {
  const int*   x      = (const int*)  d_in[0];
  const float* hidden = (const float*)d_in[1];
  const float* embW   = (const float*)d_in[2];
  const float* Wx0    = (const float*)d_in[3];
  const float* Wh0    = (const float*)d_in[4];
  const float* b0     = (const float*)d_in[5];
  const float* Wx1    = (const float*)d_in[6];
  const float* Wh1    = (const float*)d_in[7];
  const float* b1     = (const float*)d_in[8];
  const float* outb   = (const float*)d_in[9];
  float* out = (float*)d_out;

  char* ws = (char*)d_ws;
  size_t off = 0;
  auto alloc = [&](size_t bytes) {
    char* p = ws + off; off += (bytes + 255) & ~(size_t)255; return p;
  };
  u16*   embB = (u16*)  alloc((size_t)VOCAB * EMB * 2);
  u16*   Wx0T = (u16*)  alloc((size_t)EMB * HID * 2);
  u16*   Wh0T = (u16*)  alloc((size_t)HID * HID * 2);
  u16*   Wx1T = (u16*)  alloc((size_t)HID * HID * 2);
  u16*   Wh1T = (u16*)  alloc((size_t)HID * HID * 2);
  u16*   E    = (u16*)  alloc((size_t)MROWS * EMB * 2);
  float* X0f  = (float*)alloc((size_t)MROWS * HID * 4);
  u16*   H0   = (u16*)  alloc((size_t)MROWS * HID * 2);
  u16*   H1   = (u16*)  alloc((size_t)MROWS * HID * 2);
  u16*   h0i  = (u16*)  alloc((size_t)BATCH * HID * 2);
  u16*   h1i  = (u16*)  alloc((size_t)BATCH * HID * 2);
  unsigned* flags = (unsigned*)alloc(16384 * 4);   // cnt0[256], cnt1[256], 128B-strided
  if (off > ws_size) return;

  cvt_hidden<<<dim3(128), dim3(256), 0, stream>>>(hidden, h0i, h1i, flags);

  dim3 tb(32, 8), tg(32, 32);
  transpose_cvt<<<tg, tb, 0, stream>>>(Wx0, Wx0T);
  transpose_cvt<<<tg, tb, 0, stream>>>(Wh0, Wh0T);
  transpose_cvt<<<tg, tb, 0, stream>>>(Wx1, Wx1T);
  transpose_cvt<<<tg, tb, 0, stream>>>(Wh1, Wh1T);

  cvt_emb<<<dim3(2048), dim3(256), 0, stream>>>(
      (const float4*)embW, (ushort4*)embB, (int)((size_t)VOCAB * EMB / 4));
  gather_emb<<<dim3(MROWS), dim3(256), 0, stream>>>(x, embW, E);

  // X0 = E @ Wx0^T + b0   (4096x1024)
  gemm_bt<0><<<dim3(HID / 128, MROWS / 128), dim3(256), 0, stream>>>(
      E, Wx0T, b0, X0f, MROWS, HID, EMB);

  // fused recurrence: writes H0, H1 and final hidden into d_out tail
  recurrence<<<dim3(NBLK), dim3(512), 0, stream>>>(
      Wh0T, Wx1T, Wh1T, X0f, b1, h0i, h1i, H0, H1,
      out + (size_t)BATCH * SEQ * VOCAB, flags);

  // logits = H1 @ emb^T + out_b   (4096x32000, remapped to (B,T,V))
  gemm_bt<1><<<dim3(VOCAB / 128, MROWS / 128), dim3(256), 0, stream>>>(
      H1, embB, outb, out, MROWS, VOCAB, EMB);
}